// Round 5
// baseline (88.444 us; speedup 1.0000x reference)
//
#include <hip/hip_runtime.h>

// ---------------------------------------------------------------------------
// AtomicLinear == x @ W^T + bias.  M=8192, N=2048, K=2048, fp32 in/out.
// R5: read-AHEAD pipeline. 256x256 tile, BK=64, 2 LDS dbuf (128 KiB), 8 waves.
// Phase p issues ds_reads for phase p+1; counted lgkmcnt({8,4,0}) SSA-tied to
// the consumed frags keeps next-phase reads in flight through each 16-MFMA
// cluster. Stages: ph1 = A-halves(t+1), ph2 = B-halves(t+1); cross-wave
// residency gated by vmcnt(4)@ph1-tail / vmcnt(2)@ph3-tail (each wave drains
// ITS OWN stage loads before the barrier readers cross). vmcnt/lgkm never
// drain to 0 in the steady loop.
// ---------------------------------------------------------------------------

typedef short          bf16x8  __attribute__((ext_vector_type(8)));
typedef unsigned short ushort8 __attribute__((ext_vector_type(8)));
typedef float          f32x4   __attribute__((ext_vector_type(4)));

static constexpr int Mdim = 8192, Ndim = 2048, Kdim = 2048;
static constexpr int BK4 = 64;
static constexpr int KT4 = Kdim / BK4;        // 32 K-tiles
static constexpr int TB4 = 256 * BK4 * 2;     // 32768 B per 256x64 tile

__device__ __forceinline__ unsigned short f2bf(float f) {
    unsigned u = __float_as_uint(f);
    u += 0x7fffu + ((u >> 16) & 1u);
    return (unsigned short)(u >> 16);
}

// Prepass (validated R4): fp32 row-major -> half-grouped swizzled bf16 image.
// Tile image: [half0 16KB][half1 16KB]; half = 128 prows x 128 B; prow p holds
// 8 slots of 16B, slot = c ^ (p&7), c = K-chunk 0..7.
template <bool ISA>
__global__ void conv4(const float* __restrict__ src, unsigned short* __restrict__ dst) {
    int g    = blockIdx.x * 256 + threadIdx.x;
    int tile = g >> 11;
    int idx  = g & 2047;
    int h    = idx >> 10;
    int rem  = idx & 1023;
    int p    = rem >> 3, s = rem & 7;
    int c    = s ^ (p & 7);
    int kt   = tile & 31, rt = tile >> 5;
    int r;
    if constexpr (ISA) r = (p >> 6) * 128 + h * 64 + (p & 63);
    else               r = (p >> 5) * 64  + h * 32 + (p & 31);

    const float* q = src + (size_t)(rt * 256 + r) * 2048 + kt * 64 + c * 8;
    float4 v0 = *(const float4*)q;
    float4 v1 = *(const float4*)(q + 4);
    ushort8 o;
    o[0] = f2bf(v0.x); o[1] = f2bf(v0.y); o[2] = f2bf(v0.z); o[3] = f2bf(v0.w);
    o[4] = f2bf(v1.x); o[5] = f2bf(v1.y); o[6] = f2bf(v1.z); o[7] = f2bf(v1.w);
    *(ushort8*)(dst + (size_t)g * 8) = o;
}

#define GL_LDS16(gsrc, ldst)                                                    \
    __builtin_amdgcn_global_load_lds(                                           \
        (const __attribute__((address_space(1))) void*)(gsrc),                  \
        (__attribute__((address_space(3))) void*)(ldst), 16, 0, 0)

__device__ __forceinline__ void stage_half(const char* src, char* smem,
                                           unsigned ldsoff, int tid) {
    GL_LDS16(src + tid * 16,        smem + ldsoff + tid * 16);
    GL_LDS16(src + 8192 + tid * 16, smem + ldsoff + 8192 + tid * 16);
}

template <int OFF>
__device__ __forceinline__ void readA8(bf16x8 (&af)[4][2], unsigned k0, unsigned k1) {
#pragma unroll
    for (int mi = 0; mi < 4; ++mi) {
        asm volatile("ds_read_b128 %0, %1 offset:%2"
                     : "=v"(af[mi][0]) : "v"(k0), "i"(OFF + mi * 2048));
        asm volatile("ds_read_b128 %0, %1 offset:%2"
                     : "=v"(af[mi][1]) : "v"(k1), "i"(OFF + mi * 2048));
    }
}
template <int OFF>
__device__ __forceinline__ void readB4(bf16x8 (&bf)[2][2], unsigned k0, unsigned k1) {
#pragma unroll
    for (int ni = 0; ni < 2; ++ni) {
        asm volatile("ds_read_b128 %0, %1 offset:%2"
                     : "=v"(bf[ni][0]) : "v"(k0), "i"(OFF + ni * 2048));
        asm volatile("ds_read_b128 %0, %1 offset:%2"
                     : "=v"(bf[ni][1]) : "v"(k1), "i"(OFF + ni * 2048));
    }
}

// Counted lgkm waits, SSA-tied to exactly the regs the next MFMAs consume.
#define TIE12N(n, af, bf)                                                       \
    asm volatile("s_waitcnt lgkmcnt(" #n ")"                                    \
                 : "+v"(af[0][0]), "+v"(af[0][1]), "+v"(af[1][0]),              \
                   "+v"(af[1][1]), "+v"(af[2][0]), "+v"(af[2][1]),              \
                   "+v"(af[3][0]), "+v"(af[3][1]), "+v"(bf[0][0]),              \
                   "+v"(bf[0][1]), "+v"(bf[1][0]), "+v"(bf[1][1]))
#define TIE8N(n, af)                                                            \
    asm volatile("s_waitcnt lgkmcnt(" #n ")"                                    \
                 : "+v"(af[0][0]), "+v"(af[0][1]), "+v"(af[1][0]),              \
                   "+v"(af[1][1]), "+v"(af[2][0]), "+v"(af[2][1]),              \
                   "+v"(af[3][0]), "+v"(af[3][1]))
#define TIE4N(n, bf)                                                            \
    asm volatile("s_waitcnt lgkmcnt(" #n ")"                                    \
                 : "+v"(bf[0][0]), "+v"(bf[0][1]), "+v"(bf[1][0]), "+v"(bf[1][1]))

template <int RB, int CB>
__device__ __forceinline__ void mfmaQ(f32x4 acc[8][4], bf16x8 (&af)[4][2],
                                      bf16x8 (&bf)[2][2]) {
    __builtin_amdgcn_s_setprio(1);
#pragma unroll
    for (int kk = 0; kk < 2; ++kk)
#pragma unroll
        for (int mi = 0; mi < 4; ++mi)
#pragma unroll
            for (int ni = 0; ni < 2; ++ni)
                acc[RB + mi][CB + ni] = __builtin_amdgcn_mfma_f32_16x16x32_bf16(
                    af[mi][kk], bf[ni][kk], acc[RB + mi][CB + ni], 0, 0, 0);
    __builtin_amdgcn_s_setprio(0);
}

#define BAR() __builtin_amdgcn_s_barrier()

// One K-tile = 4 phases, read-ahead by one phase.
// afC = A0(t), afN = (A1(t) after ph1) then A0(t+1) after ph4. bfX=B0, bfY=B1.
template <bool STG, bool RD4, int VM1, int VM3, int NXT>
__device__ __forceinline__ void tile5(
    unsigned aK0, unsigned aK1, unsigned bK0, unsigned bK1,         // cur buf
    unsigned naK0, unsigned naK1, unsigned nbK0, unsigned nbK1,     // nxt buf
    f32x4 acc[8][4],
    bf16x8 (&afC)[4][2], bf16x8 (&afN)[4][2],
    bf16x8 (&bfX)[2][2], bf16x8 (&bfY)[2][2],
    const char* gAn, const char* gBn, char* smem, int tid) {
    // ph1: issue A1(t) reads; stage A0,A1(t+1); MFMA Q1=(A0,B0)
    readA8<16384>(afN, aK0, aK1);
    if constexpr (STG) {
        stage_half(gAn,         smem, NXT + 0,     tid);
        stage_half(gAn + 16384, smem, NXT + 16384, tid);
    }
    BAR();
    TIE12N(8, afC, bfX);                  // A0,B0 done; A1's 8 stay in flight
    mfmaQ<0, 0>(acc, afC, bfX);
    if constexpr (VM1 == 4)      asm volatile("s_waitcnt vmcnt(4)" ::: "memory");
    else if constexpr (VM1 == 0) asm volatile("s_waitcnt vmcnt(0)" ::: "memory");
    BAR();
    // ph2: issue B1(t) reads; stage B0,B1(t+1); MFMA Q2=(A1,B0)
    readB4<16384>(bfY, bK0, bK1);
    if constexpr (STG) {
        stage_half(gBn,         smem, NXT + 32768, tid);
        stage_half(gBn + 16384, smem, NXT + 49152, tid);
    }
    BAR();
    TIE8N(4, afN);                        // A1 done; B1's 4 stay in flight
    mfmaQ<4, 0>(acc, afN, bfX);
    BAR();
    // ph3: MFMA Q3=(A1,B1)
    TIE4N(0, bfY);                        // B1 done (nothing else outstanding)
    mfmaQ<4, 2>(acc, afN, bfY);
    if constexpr (VM3 == 2) asm volatile("s_waitcnt vmcnt(2)" ::: "memory");
    BAR();
    // ph4: issue A0(t+1),B0(t+1) reads from nxt buf; MFMA Q4=(A0,B1)
    if constexpr (RD4) {
        readA8<0>(afN, naK0, naK1);
        readB4<0>(bfX, nbK0, nbK1);
    }
    BAR();
    mfmaQ<0, 2>(acc, afC, bfY);           // operands already waited; 12 reads fly
    BAR();
}

// 256x256 block tile, 512 threads (8 waves 2M x 4N), wave tile 128x64.
__global__ __launch_bounds__(512, 2) void gemm5(
    const unsigned short* __restrict__ xa, const unsigned short* __restrict__ wb,
    const float* __restrict__ bias, float* __restrict__ out) {
    extern __shared__ char smem[];               // 2 bufs x 64 KB

    const int tid  = threadIdx.x;
    const int lane = tid & 63, wid = tid >> 6;
    const int wr   = wid >> 2;                   // 0..1
    const int wc   = wid & 3;                    // 0..3
    const int fr   = lane & 15, fq = lane >> 4;

    const int bid = blockIdx.x;                  // 256 blocks = 1/CU
    const int nt  = bid & 7;                     // XCD-local B panel (T1)
    const int mt  = bid >> 3;                    // 0..31

    const char* aT = (const char*)xa + (size_t)mt * KT4 * TB4;
    const char* bT = (const char*)wb + (size_t)nt * KT4 * TB4;

    const unsigned lds0  = (unsigned)(size_t)smem;
    const int slot0 = fq ^ (fr & 7);
    const int slot1 = (4 + fq) ^ (fr & 7);
    const unsigned aRow = (unsigned)((wr * 64 + fr) * 128);
    const unsigned bRow = (unsigned)((wc * 32 + fr) * 128);
    const unsigned aK0_0 = lds0 + aRow + slot0 * 16;
    const unsigned aK1_0 = lds0 + aRow + slot1 * 16;
    const unsigned bK0_0 = lds0 + 32768u + bRow + slot0 * 16;
    const unsigned bK1_0 = lds0 + 32768u + bRow + slot1 * 16;
    const unsigned aK0_1 = aK0_0 + 65536u, aK1_1 = aK1_0 + 65536u;
    const unsigned bK0_1 = bK0_0 + 65536u, bK1_1 = bK1_0 + 65536u;

    f32x4 acc[8][4];
#pragma unroll
    for (int i = 0; i < 8; ++i)
#pragma unroll
        for (int j = 0; j < 4; ++j)
            acc[i][j] = f32x4{0.f, 0.f, 0.f, 0.f};
    bf16x8 afX[4][2], afY[4][2], bfX[2][2], bfY[2][2];

    // Prologue: stage tile0 (queue order A0,A1,B0,B1); drain to B1; read S1(0).
    stage_half(aT,          smem, 0,     tid);
    stage_half(aT + 16384,  smem, 16384, tid);
    stage_half(bT,          smem, 32768, tid);
    stage_half(bT + 16384,  smem, 49152, tid);
    asm volatile("s_waitcnt vmcnt(2)" ::: "memory");   // A0,A1,B0 resident
    BAR();
    readA8<0>(afX, aK0_0, aK1_0);                      // A0(0): 8 reads
    readB4<0>(bfX, bK0_0, bK1_0);                      // B0(0): 4 reads

    // Steady: 15 iters x {even tile 2i (buf0), odd tile 2i+1 (buf1)}.
#pragma unroll 1
    for (int it = 0; it < 15; ++it) {
        const char* aE = aT + (size_t)(2 * it + 1) * TB4;   // stage src for t+1
        const char* bE = bT + (size_t)(2 * it + 1) * TB4;
        tile5<true, true, 4, 2, 65536>(aK0_0, aK1_0, bK0_0, bK1_0,
                                       aK0_1, aK1_1, bK0_1, bK1_1,
                                       acc, afX, afY, bfX, bfY,
                                       aE, bE, smem, tid);
        tile5<true, true, 4, 2, 0>(aK0_1, aK1_1, bK0_1, bK1_1,
                                   aK0_0, aK1_0, bK0_0, bK1_0,
                                   acc, afY, afX, bfX, bfY,
                                   aE + TB4, bE + TB4, smem, tid);
    }
    // t=30 (even, steady; stages tile31), t=31 (odd, last).
    {
        const char* a31 = aT + (size_t)31 * TB4;
        const char* b31 = bT + (size_t)31 * TB4;
        tile5<true, true, 4, 2, 65536>(aK0_0, aK1_0, bK0_0, bK1_0,
                                       aK0_1, aK1_1, bK0_1, bK1_1,
                                       acc, afX, afY, bfX, bfY,
                                       a31, b31, smem, tid);
        tile5<false, false, 0, -1, 0>(aK0_1, aK1_1, bK0_1, bK1_1,
                                      aK0_0, aK1_0, bK0_0, bK1_0,
                                      acc, afY, afX, bfX, bfY,
                                      aT, bT, smem, tid);
    }

    // Epilogue (validated R4): acc[ar][ac]:
    // row = wr*128 + (ar>>2)*64 + (ar&3)*16 + fq*4 + rr;
    // col = wc*64  + (ac>>1)*32 + (ac&1)*16 + fr.
    const int gr0 = mt * 256 + wr * 128 + fq * 4;
    const int gc0 = nt * 256 + wc * 64;
#pragma unroll
    for (int ac = 0; ac < 4; ++ac) {
        const int cn = gc0 + (ac >> 1) * 32 + (ac & 1) * 16 + fr;
        const float bv = bias[cn];
#pragma unroll
        for (int ar = 0; ar < 8; ++ar) {
            const int rm = gr0 + (ar >> 2) * 64 + (ar & 3) * 16;
#pragma unroll
            for (int rr = 0; rr < 4; ++rr)
                out[(size_t)(rm + rr) * Ndim + cn] = acc[ar][ac][rr] + bv;
        }
    }
}

// Correct-but-slow fp32 fallback if workspace is too small for bf16 copies.
__global__ void fallback_gemm(const float* __restrict__ x, const float* __restrict__ w,
                              const float* __restrict__ bias, float* __restrict__ out) {
    __shared__ float As[64][17];
    __shared__ float Bs[64][17];
    int tx = threadIdx.x & 15, ty = threadIdx.x >> 4;
    int m0 = blockIdx.y * 64, n0 = blockIdx.x * 64;
    float acc[4][4] = {};
    for (int k0 = 0; k0 < Kdim; k0 += 16) {
#pragma unroll
        for (int i = 0; i < 4; ++i) {
            int idx = threadIdx.x + i * 256;
            int rr = idx >> 4, cc = idx & 15;
            As[rr][cc] = x[(size_t)(m0 + rr) * Kdim + k0 + cc];
            Bs[rr][cc] = w[(size_t)(n0 + rr) * Kdim + k0 + cc];
        }
        __syncthreads();
#pragma unroll
        for (int kk = 0; kk < 16; ++kk) {
            float a[4], b[4];
#pragma unroll
            for (int i = 0; i < 4; ++i) a[i] = As[ty * 4 + i][kk];
#pragma unroll
            for (int j = 0; j < 4; ++j) b[j] = Bs[tx * 4 + j][kk];
#pragma unroll
            for (int i = 0; i < 4; ++i)
#pragma unroll
                for (int j = 0; j < 4; ++j) acc[i][j] += a[i] * b[j];
        }
        __syncthreads();
    }
#pragma unroll
    for (int i = 0; i < 4; ++i)
#pragma unroll
        for (int j = 0; j < 4; ++j) {
            int gm = m0 + ty * 4 + i, gn = n0 + tx * 4 + j;
            out[(size_t)gm * Ndim + gn] = acc[i][j] + bias[gn];
        }
}

extern "C" void kernel_launch(void* const* d_in, const int* in_sizes, int n_in,
                              void* d_out, int out_size, void* d_ws, size_t ws_size,
                              hipStream_t stream) {
    const float* x    = (const float*)d_in[0];
    const float* w    = (const float*)d_in[1];
    const float* bias = (const float*)d_in[2];
    float* out        = (float*)d_out;

    const size_t needA = (size_t)Mdim * Kdim * sizeof(unsigned short);
    const size_t needB = (size_t)Ndim * Kdim * sizeof(unsigned short);

    if (ws_size >= needA + needB) {
        unsigned short* xa = (unsigned short*)d_ws;
        unsigned short* wb = xa + (size_t)Mdim * Kdim;
        conv4<true><<<(Mdim * Kdim / 8) / 256, 256, 0, stream>>>(x, xa);
        conv4<false><<<(Ndim * Kdim / 8) / 256, 256, 0, stream>>>(w, wb);

        (void)hipFuncSetAttribute((const void*)gemm5,
                                  hipFuncAttributeMaxDynamicSharedMemorySize,
                                  131072);
        gemm5<<<(Mdim / 256) * (Ndim / 256), 512, 131072, stream>>>(
            xa, wb, bias, out);
    } else {
        dim3 grid(Ndim / 64, Mdim / 64);
        fallback_gemm<<<grid, 256, 0, stream>>>(x, w, bias, out);
    }
}

// Round 6
// 83.204 us; speedup vs baseline: 1.0630x; 1.0630x over previous
//
#include <hip/hip_runtime.h>

// ---------------------------------------------------------------------------
// AtomicLinear == x @ W^T + bias.  M=8192, N=2048, K=2048, fp32 in/out.
// R6: AITER-style 1:1 interleave. 256x256 tile, BK=64, 2 LDS dbuf, 8 waves.
// All MFMAs are inline-asm ("+a" acc) so the ds_read/global_load_lds/MFMA
// interleave is pinned verbatim into the .s: each MFMA's issue-stall gap is
// where the same wave issues the NEXT phase's LDS reads -> LDS window hides
// under the matrix window. lgkm0 at phase entry waits reads that completed
// under the previous cluster. One vmcnt(4) gate per tile; 1 barrier/phase.
// ---------------------------------------------------------------------------

typedef short          bf16x8  __attribute__((ext_vector_type(8)));
typedef unsigned short ushort8 __attribute__((ext_vector_type(8)));
typedef float          f32x4   __attribute__((ext_vector_type(4)));

static constexpr int Mdim = 8192, Ndim = 2048, Kdim = 2048;
static constexpr int KT4 = 32;                // K-tiles of BK=64
static constexpr int TB4 = 256 * 64 * 2;      // 32768 B per 256x64 tile

__device__ __forceinline__ unsigned short f2bf(float f) {
    unsigned u = __float_as_uint(f);
    u += 0x7fffu + ((u >> 16) & 1u);
    return (unsigned short)(u >> 16);
}

// Prepass (validated R4/R5): fp32 row-major -> half-grouped swizzled bf16.
// Tile image: [half0 16KB][half1 16KB]; half = 128 prows x 128 B; prow p has
// 8 slots of 16B, slot = c ^ (p&7), c = K-chunk 0..7.
template <bool ISA>
__global__ void conv4(const float* __restrict__ src, unsigned short* __restrict__ dst) {
    int g    = blockIdx.x * 256 + threadIdx.x;
    int tile = g >> 11;
    int idx  = g & 2047;
    int h    = idx >> 10;
    int rem  = idx & 1023;
    int p    = rem >> 3, s = rem & 7;
    int c    = s ^ (p & 7);
    int kt   = tile & 31, rt = tile >> 5;
    int r;
    if constexpr (ISA) r = (p >> 6) * 128 + h * 64 + (p & 63);
    else               r = (p >> 5) * 64  + h * 32 + (p & 31);

    const float* q = src + (size_t)(rt * 256 + r) * 2048 + kt * 64 + c * 8;
    float4 v0 = *(const float4*)q;
    float4 v1 = *(const float4*)(q + 4);
    ushort8 o;
    o[0] = f2bf(v0.x); o[1] = f2bf(v0.y); o[2] = f2bf(v0.z); o[3] = f2bf(v0.w);
    o[4] = f2bf(v1.x); o[5] = f2bf(v1.y); o[6] = f2bf(v1.z); o[7] = f2bf(v1.w);
    *(ushort8*)(dst + (size_t)g * 8) = o;
}

#define GL_LDS16(gsrc, ldst)                                                    \
    __builtin_amdgcn_global_load_lds(                                           \
        (const __attribute__((address_space(1))) void*)(gsrc),                  \
        (__attribute__((address_space(3))) void*)(ldst), 16, 0, 0)

#define DSR(dst, base, OFF)                                                     \
    asm volatile("ds_read_b128 %0, %1 offset:%2" : "=v"(dst) : "v"(base), "i"(OFF))

#define BAR() __builtin_amdgcn_s_barrier()

#define TIE12(af, bf)                                                           \
    asm volatile("s_waitcnt lgkmcnt(0)"                                         \
                 : "+v"(af[0][0]), "+v"(af[0][1]), "+v"(af[1][0]),              \
                   "+v"(af[1][1]), "+v"(af[2][0]), "+v"(af[2][1]),              \
                   "+v"(af[3][0]), "+v"(af[3][1]), "+v"(bf[0][0]),              \
                   "+v"(bf[0][1]), "+v"(bf[1][0]), "+v"(bf[1][1]))
#define TIE8(af)                                                                \
    asm volatile("s_waitcnt lgkmcnt(0)"                                         \
                 : "+v"(af[0][0]), "+v"(af[0][1]), "+v"(af[1][0]),              \
                   "+v"(af[1][1]), "+v"(af[2][0]), "+v"(af[2][1]),              \
                   "+v"(af[3][0]), "+v"(af[3][1]))
#define TIE4(bf)                                                                \
    asm volatile("s_waitcnt lgkmcnt(0)"                                         \
                 : "+v"(bf[0][0]), "+v"(bf[0][1]), "+v"(bf[1][0]), "+v"(bf[1][1]))

// One K-tile, 4 phases, reads for phase p+1 interleaved INSIDE phase p's MFMAs.
// Quadrants: ph1 Q(afX,bf0) ph2 Q(afX,bf1) ph3 Q(afY,bf1) ph4 Q(afY,bf0).
// bf0/bf1 swap roles per tile (caller); afX rewritten with A0(t+1) in ph3.
template <int VM, bool STG, bool RDN>
__device__ __forceinline__ void tile6(
    f32x4 (&acc)[8][4],
    bf16x8 (&afX)[4][2], bf16x8 (&afY)[4][2],
    bf16x8 (&bf0)[2][2], bf16x8 (&bf1)[2][2],
    unsigned aK0, unsigned aK1, unsigned bK0, unsigned bK1,      // cur buf
    unsigned naK0, unsigned naK1, unsigned nbK0, unsigned nbK1,  // nxt buf
    const char* gA2, const char* gB2, char* ldsA, char* ldsB, int tid) {

#define M_(R, C, AF, BF, KK)                                                    \
    asm volatile("v_mfma_f32_16x16x32_bf16 %0, %1, %2, %0"                      \
                 : "+a"(acc[R][C]) : "v"(AF[(R) & 3][KK]), "v"(BF[(C) & 1][KK]))

    // ---- phase 1: Q(afX, bf0); reads bf1 <- B1(t) ----
    BAR();
    TIE12(afX, bf0);
    __builtin_amdgcn_s_setprio(1);
    M_(0, 0, afX, bf0, 0); M_(0, 1, afX, bf0, 0);
    DSR(bf1[0][0], bK0, 16384);
    M_(1, 0, afX, bf0, 0); M_(1, 1, afX, bf0, 0);
    DSR(bf1[0][1], bK1, 16384);
    M_(2, 0, afX, bf0, 0); M_(2, 1, afX, bf0, 0);
    DSR(bf1[1][0], bK0, 18432);
    M_(3, 0, afX, bf0, 0); M_(3, 1, afX, bf0, 0);
    DSR(bf1[1][1], bK1, 18432);
    M_(0, 0, afX, bf0, 1); M_(0, 1, afX, bf0, 1);
    M_(1, 0, afX, bf0, 1); M_(1, 1, afX, bf0, 1);
    M_(2, 0, afX, bf0, 1); M_(2, 1, afX, bf0, 1);
    M_(3, 0, afX, bf0, 1); M_(3, 1, afX, bf0, 1);
    __builtin_amdgcn_s_setprio(0);

    // ---- phase 2: Q(afX, bf1); reads afY <- A1(t); stage B(t+2); gate ----
    BAR();
    TIE4(bf1);
    __builtin_amdgcn_s_setprio(1);
    M_(0, 2, afX, bf1, 0); M_(0, 3, afX, bf1, 0);
    DSR(afY[0][0], aK0, 16384); DSR(afY[0][1], aK1, 16384);
    if constexpr (STG) GL_LDS16(gB2 + tid * 16, ldsB + tid * 16);
    M_(1, 2, afX, bf1, 0); M_(1, 3, afX, bf1, 0);
    DSR(afY[1][0], aK0, 18432); DSR(afY[1][1], aK1, 18432);
    if constexpr (STG) GL_LDS16(gB2 + 8192 + tid * 16, ldsB + 8192 + tid * 16);
    M_(2, 2, afX, bf1, 0); M_(2, 3, afX, bf1, 0);
    DSR(afY[2][0], aK0, 20480); DSR(afY[2][1], aK1, 20480);
    if constexpr (STG) GL_LDS16(gB2 + 16384 + tid * 16, ldsB + 16384 + tid * 16);
    M_(3, 2, afX, bf1, 0); M_(3, 3, afX, bf1, 0);
    DSR(afY[3][0], aK0, 22528); DSR(afY[3][1], aK1, 22528);
    if constexpr (STG) GL_LDS16(gB2 + 24576 + tid * 16, ldsB + 24576 + tid * 16);
    M_(0, 2, afX, bf1, 1); M_(0, 3, afX, bf1, 1);
    M_(1, 2, afX, bf1, 1); M_(1, 3, afX, bf1, 1);
    M_(2, 2, afX, bf1, 1); M_(2, 3, afX, bf1, 1);
    M_(3, 2, afX, bf1, 1); M_(3, 3, afX, bf1, 1);
    __builtin_amdgcn_s_setprio(0);
    if constexpr (VM == 4)      asm volatile("s_waitcnt vmcnt(4)" ::: "memory");
    else if constexpr (VM == 0) asm volatile("s_waitcnt vmcnt(0)" ::: "memory");

    // ---- phase 3: Q(afY, bf1); reads afX <- A0(t+1); stage A(t+2) ----
    BAR();
    TIE8(afY);
    __builtin_amdgcn_s_setprio(1);
    M_(4, 2, afY, bf1, 0); M_(4, 3, afY, bf1, 0);
    if constexpr (RDN) { DSR(afX[0][0], naK0, 0); DSR(afX[0][1], naK1, 0); }
    if constexpr (STG) GL_LDS16(gA2 + tid * 16, ldsA + tid * 16);
    M_(5, 2, afY, bf1, 0); M_(5, 3, afY, bf1, 0);
    if constexpr (RDN) { DSR(afX[1][0], naK0, 2048); DSR(afX[1][1], naK1, 2048); }
    if constexpr (STG) GL_LDS16(gA2 + 8192 + tid * 16, ldsA + 8192 + tid * 16);
    M_(6, 2, afY, bf1, 0); M_(6, 3, afY, bf1, 0);
    if constexpr (RDN) { DSR(afX[2][0], naK0, 4096); DSR(afX[2][1], naK1, 4096); }
    if constexpr (STG) GL_LDS16(gA2 + 16384 + tid * 16, ldsA + 16384 + tid * 16);
    M_(7, 2, afY, bf1, 0); M_(7, 3, afY, bf1, 0);
    if constexpr (RDN) { DSR(afX[3][0], naK0, 6144); DSR(afX[3][1], naK1, 6144); }
    if constexpr (STG) GL_LDS16(gA2 + 24576 + tid * 16, ldsA + 24576 + tid * 16);
    M_(4, 2, afY, bf1, 1); M_(4, 3, afY, bf1, 1);
    M_(5, 2, afY, bf1, 1); M_(5, 3, afY, bf1, 1);
    M_(6, 2, afY, bf1, 1); M_(6, 3, afY, bf1, 1);
    M_(7, 2, afY, bf1, 1); M_(7, 3, afY, bf1, 1);
    __builtin_amdgcn_s_setprio(0);

    // ---- phase 4: Q(afY, bf0); reads bf1 <- B0(t+1) (becomes next bf0) ----
    BAR();
    __builtin_amdgcn_s_setprio(1);
    M_(4, 0, afY, bf0, 0); M_(4, 1, afY, bf0, 0);
    if constexpr (RDN) DSR(bf1[0][0], nbK0, 0);
    M_(5, 0, afY, bf0, 0); M_(5, 1, afY, bf0, 0);
    if constexpr (RDN) DSR(bf1[0][1], nbK1, 0);
    M_(6, 0, afY, bf0, 0); M_(6, 1, afY, bf0, 0);
    if constexpr (RDN) DSR(bf1[1][0], nbK0, 2048);
    M_(7, 0, afY, bf0, 0); M_(7, 1, afY, bf0, 0);
    if constexpr (RDN) DSR(bf1[1][1], nbK1, 2048);
    M_(4, 0, afY, bf0, 1); M_(4, 1, afY, bf0, 1);
    M_(5, 0, afY, bf0, 1); M_(5, 1, afY, bf0, 1);
    M_(6, 0, afY, bf0, 1); M_(6, 1, afY, bf0, 1);
    M_(7, 0, afY, bf0, 1); M_(7, 1, afY, bf0, 1);
    __builtin_amdgcn_s_setprio(0);
#undef M_
}

// 256x256 block tile, 512 threads (8 waves 2M x 4N), wave tile 128x64.
__global__ __launch_bounds__(512, 2) void gemm6(
    const unsigned short* __restrict__ xa, const unsigned short* __restrict__ wb,
    const float* __restrict__ bias, float* __restrict__ out) {
    extern __shared__ char smem[];               // 2 bufs x 64 KB

    const int tid  = threadIdx.x;
    const int lane = tid & 63, wid = tid >> 6;
    const int wr   = wid >> 2;                   // 0..1
    const int wc   = wid & 3;                    // 0..3
    const int fr   = lane & 15, fq = lane >> 4;

    const int bid = blockIdx.x;                  // 256 blocks = 1/CU
    const int nt  = bid & 7;                     // XCD-local B panel (T1)
    const int mt  = bid >> 3;                    // 0..31

    const char* aT = (const char*)xa + (size_t)mt * KT4 * TB4;
    const char* bT = (const char*)wb + (size_t)nt * KT4 * TB4;

    const unsigned lds0  = (unsigned)(size_t)smem;
    const int slot0 = fq ^ (fr & 7);
    const int slot1 = (4 + fq) ^ (fr & 7);
    const unsigned aRow = (unsigned)((wr * 64 + fr) * 128);
    const unsigned bRow = (unsigned)((wc * 32 + fr) * 128);
    const unsigned aK0_0 = lds0 + aRow + slot0 * 16;
    const unsigned aK1_0 = lds0 + aRow + slot1 * 16;
    const unsigned bK0_0 = lds0 + 32768u + bRow + slot0 * 16;
    const unsigned bK1_0 = lds0 + 32768u + bRow + slot1 * 16;
    const unsigned aK0_1 = aK0_0 + 65536u, aK1_1 = aK1_0 + 65536u;
    const unsigned bK0_1 = bK0_0 + 65536u, bK1_1 = bK1_0 + 65536u;

    f32x4 acc[8][4];
#pragma unroll
    for (int i = 0; i < 8; ++i)
#pragma unroll
        for (int j = 0; j < 4; ++j)
            acc[i][j] = f32x4{0.f, 0.f, 0.f, 0.f};
    bf16x8 afX[4][2], afY[4][2], bfX[2][2], bfY[2][2];

    // Prologue: tile0 resident; tile1 staged (B then A = steady age order);
    // initial reads A0(0)->afX, B0(0)->bfX.
    GL_LDS16(aT + tid * 16,         smem + tid * 16);
    GL_LDS16(aT + 8192 + tid * 16,  smem + 8192 + tid * 16);
    GL_LDS16(aT + 16384 + tid * 16, smem + 16384 + tid * 16);
    GL_LDS16(aT + 24576 + tid * 16, smem + 24576 + tid * 16);
    GL_LDS16(bT + tid * 16,         smem + 32768 + tid * 16);
    GL_LDS16(bT + 8192 + tid * 16,  smem + 40960 + tid * 16);
    GL_LDS16(bT + 16384 + tid * 16, smem + 49152 + tid * 16);
    GL_LDS16(bT + 24576 + tid * 16, smem + 57344 + tid * 16);
    asm volatile("s_waitcnt vmcnt(0)" ::: "memory");
    BAR();
    {   // stage tile1: B(1) then A(1)
        const char* a1 = aT + TB4;
        const char* b1 = bT + TB4;
        GL_LDS16(b1 + tid * 16,         smem + 98304 + tid * 16);
        GL_LDS16(b1 + 8192 + tid * 16,  smem + 106496 + tid * 16);
        GL_LDS16(b1 + 16384 + tid * 16, smem + 114688 + tid * 16);
        GL_LDS16(b1 + 24576 + tid * 16, smem + 122880 + tid * 16);
        GL_LDS16(a1 + tid * 16,         smem + 65536 + tid * 16);
        GL_LDS16(a1 + 8192 + tid * 16,  smem + 73728 + tid * 16);
        GL_LDS16(a1 + 16384 + tid * 16, smem + 81920 + tid * 16);
        GL_LDS16(a1 + 24576 + tid * 16, smem + 90112 + tid * 16);
    }
    DSR(afX[0][0], aK0_0, 0);    DSR(afX[0][1], aK1_0, 0);
    DSR(afX[1][0], aK0_0, 2048); DSR(afX[1][1], aK1_0, 2048);
    DSR(afX[2][0], aK0_0, 4096); DSR(afX[2][1], aK1_0, 4096);
    DSR(afX[3][0], aK0_0, 6144); DSR(afX[3][1], aK1_0, 6144);
    DSR(bfX[0][0], bK0_0, 0);    DSR(bfX[0][1], bK1_0, 0);
    DSR(bfX[1][0], bK0_0, 2048); DSR(bfX[1][1], bK1_0, 2048);

    // Steady: 15 iters x {even tile 2i (buf0, bf0=bfX), odd (buf1, bf0=bfY)}.
#pragma unroll 1
    for (int it = 0; it < 15; ++it) {
        const char* gA2 = aT + (size_t)(2 * it + 2) * TB4;
        const char* gB2 = bT + (size_t)(2 * it + 2) * TB4;
        tile6<4, true, true>(acc, afX, afY, bfX, bfY,
                             aK0_0, aK1_0, bK0_0, bK1_0,
                             aK0_1, aK1_1, bK0_1, bK1_1,
                             gA2, gB2, smem, smem + 32768, tid);
        tile6<4, true, true>(acc, afX, afY, bfY, bfX,
                             aK0_1, aK1_1, bK0_1, bK1_1,
                             aK0_0, aK1_0, bK0_0, bK1_0,
                             gA2 + TB4, gB2 + TB4,
                             smem + 65536, smem + 98304, tid);
    }
    // t=30 (even): no staging, gate drains tile31, reads tile31.
    tile6<0, false, true>(acc, afX, afY, bfX, bfY,
                          aK0_0, aK1_0, bK0_0, bK1_0,
                          aK0_1, aK1_1, bK0_1, bK1_1,
                          aT, bT, smem, smem + 32768, tid);
    // t=31 (odd): last tile, no next reads.
    tile6<-1, false, false>(acc, afX, afY, bfY, bfX,
                            aK0_1, aK1_1, bK0_1, bK1_1,
                            aK0_0, aK1_0, bK0_0, bK1_0,
                            aT, bT, smem + 65536, smem + 98304, tid);

    // Epilogue (validated R4/R5): acc[ar][ac]:
    // row = wr*128 + (ar>>2)*64 + (ar&3)*16 + fq*4 + rr;
    // col = wc*64  + (ac>>1)*32 + (ac&1)*16 + fr.
    const int gr0 = mt * 256 + wr * 128 + fq * 4;
    const int gc0 = nt * 256 + wc * 64;
#pragma unroll
    for (int ac = 0; ac < 4; ++ac) {
        const int cn = gc0 + (ac >> 1) * 32 + (ac & 1) * 16 + fr;
        const float bv = bias[cn];
#pragma unroll
        for (int ar = 0; ar < 8; ++ar) {
            const int rm = gr0 + (ar >> 2) * 64 + (ar & 3) * 16;
#pragma unroll
            for (int rr = 0; rr < 4; ++rr)
                out[(size_t)(rm + rr) * Ndim + cn] = acc[ar][ac][rr] + bv;
        }
    }
}

// Correct-but-slow fp32 fallback if workspace is too small for bf16 copies.
__global__ void fallback_gemm(const float* __restrict__ x, const float* __restrict__ w,
                              const float* __restrict__ bias, float* __restrict__ out) {
    __shared__ float As[64][17];
    __shared__ float Bs[64][17];
    int tx = threadIdx.x & 15, ty = threadIdx.x >> 4;
    int m0 = blockIdx.y * 64, n0 = blockIdx.x * 64;
    float acc[4][4] = {};
    for (int k0 = 0; k0 < Kdim; k0 += 16) {
#pragma unroll
        for (int i = 0; i < 4; ++i) {
            int idx = threadIdx.x + i * 256;
            int rr = idx >> 4, cc = idx & 15;
            As[rr][cc] = x[(size_t)(m0 + rr) * Kdim + k0 + cc];
            Bs[rr][cc] = w[(size_t)(n0 + rr) * Kdim + k0 + cc];
        }
        __syncthreads();
#pragma unroll
        for (int kk = 0; kk < 16; ++kk) {
            float a[4], b[4];
#pragma unroll
            for (int i = 0; i < 4; ++i) a[i] = As[ty * 4 + i][kk];
#pragma unroll
            for (int j = 0; j < 4; ++j) b[j] = Bs[tx * 4 + j][kk];
#pragma unroll
            for (int i = 0; i < 4; ++i)
#pragma unroll
                for (int j = 0; j < 4; ++j) acc[i][j] += a[i] * b[j];
        }
        __syncthreads();
    }
#pragma unroll
    for (int i = 0; i < 4; ++i)
#pragma unroll
        for (int j = 0; j < 4; ++j) {
            int gm = m0 + ty * 4 + i, gn = n0 + tx * 4 + j;
            out[(size_t)gm * Ndim + gn] = acc[i][j] + bias[gn];
        }
}

extern "C" void kernel_launch(void* const* d_in, const int* in_sizes, int n_in,
                              void* d_out, int out_size, void* d_ws, size_t ws_size,
                              hipStream_t stream) {
    const float* x    = (const float*)d_in[0];
    const float* w    = (const float*)d_in[1];
    const float* bias = (const float*)d_in[2];
    float* out        = (float*)d_out;

    const size_t needA = (size_t)Mdim * Kdim * sizeof(unsigned short);
    const size_t needB = (size_t)Ndim * Kdim * sizeof(unsigned short);

    if (ws_size >= needA + needB) {
        unsigned short* xa = (unsigned short*)d_ws;
        unsigned short* wb = xa + (size_t)Mdim * Kdim;
        conv4<true><<<(Mdim * Kdim / 8) / 256, 256, 0, stream>>>(x, xa);
        conv4<false><<<(Ndim * Kdim / 8) / 256, 256, 0, stream>>>(w, wb);

        (void)hipFuncSetAttribute((const void*)gemm6,
                                  hipFuncAttributeMaxDynamicSharedMemorySize,
                                  131072);
        gemm6<<<(Mdim / 256) * (Ndim / 256), 512, 131072, stream>>>(
            xa, wb, bias, out);
    } else {
        dim3 grid(Ndim / 64, Mdim / 64);
        fallback_gemm<<<grid, 256, 0, stream>>>(x, w, bias, out);
    }
}